// Round 2
// baseline (86.413 us; speedup 1.0000x reference)
//
#include <hip/hip_runtime.h>

#define B_ 8
#define C_ 64
#define O_ 64
#define H_ 128
#define W_ 128

typedef __attribute__((ext_vector_type(8))) short bf16x8;
typedef __attribute__((ext_vector_type(4))) float f32x4;

__device__ __forceinline__ unsigned short f2bf(float v) {
    unsigned u = __float_as_uint(v);
    unsigned r = (u + 0x7FFFu + ((u >> 16) & 1u)) >> 16;   // RTNE (finite inputs)
    return (unsigned short)r;
}

// ---- weight prep: wfrag flat = (((t*2+ks)*4+fi)*64 + lane)*8 + j ----
// element = bf16( weight[(o*64 + c)*9 + t] ), o = fi*16 + (lane&15),
// c = ks*32 + ((lane>>4)&3)*8 + j   -> exact MFMA B-fragment order.
__global__ void prep_weights(const float* __restrict__ weight,
                             unsigned short* __restrict__ wfrag) {
    int idx = blockIdx.x * 256 + threadIdx.x;
    if (idx >= 9 * 4096) return;
    int j  = idx & 7;
    int l  = (idx >> 3) & 63;
    int fi = (idx >> 9) & 3;
    int ks = (idx >> 11) & 1;
    int t  = idx >> 12;
    int o  = fi * 16 + (l & 15);
    int c  = ks * 32 + ((l >> 4) & 3) * 8 + j;
    wfrag[idx] = f2bf(weight[(o * C_ + c) * 9 + t]);
}

// Tile: one (b, h, 64-px half-row) x all 64 o. 4 waves: quadrant (po, oo).
// xsT: bf16, c-innermost, XOR-swizzled: byte(rc=kh*66+col, c) =
//      rc*128 + ((c*2) ^ ((col&7)<<4))    [25,344 B]
__global__ __launch_bounds__(256, 4)
void depthconv_mfma(const float* __restrict__ x,
                    const float* __restrict__ depth,
                    const unsigned short* __restrict__ wfrag,
                    const float* __restrict__ bias,
                    float* __restrict__ out) {
    __shared__ __align__(16) unsigned char arena[25344 + 2304 + 792];
    float (*siml)[64] = (float (*)[64])(arena + 25344);          // [9][64]
    float (*dt)[66]   = (float (*)[66])(arena + 25344 + 2304);   // [3][66]
    float (*ot)[68]   = (float (*)[68])arena;                    // epilogue reuse

    const int tid = threadIdx.x;
    const int blk = blockIdx.x;
    const int b   = blk >> 8;
    const int rem = blk & 255;
    const int h   = rem >> 1;
    const int w0  = (rem & 1) * 64;

    // ---- stage depth tile ----
    for (int i = tid; i < 198; i += 256) {
        int r = i / 66, col = i - r * 66;
        int gh = h + r - 1, gw = w0 + col - 1;
        float v = 0.f;
        if ((unsigned)gh < (unsigned)H_ && (unsigned)gw < (unsigned)W_)
            v = depth[(b * H_ + gh) * W_ + gw];
        dt[r][col] = v;
    }
    __syncthreads();

    // ---- sim[t][p] = exp(-|d_tap - d_center|) ----
    for (int i = tid; i < 576; i += 256) {
        int t = i >> 6, p = i & 63;
        int kh = t / 3, kw = t - kh * 3;
        siml[t][p] = expf(-fabsf(dt[kh][p + kw] - dt[1][p + 1]));
    }
    // ---- stage x tile -> bf16, c-innermost, swizzled ----
    for (int i = tid; i < C_ * 198; i += 256) {
        int c  = i / 198;
        int rc = i - c * 198;
        int r  = rc / 66, col = rc - r * 66;
        int gh = h + r - 1, gw = w0 + col - 1;
        float v = 0.f;
        if ((unsigned)gh < (unsigned)H_ && (unsigned)gw < (unsigned)W_)
            v = x[((b * C_ + c) * H_ + gh) * W_ + gw];
        int byte = rc * 128 + ((c * 2) ^ ((col & 7) << 4));
        *(unsigned short*)(arena + byte) = f2bf(v);
    }
    __syncthreads();

    const int lane = tid & 63;
    const int wv   = tid >> 6;          // wave 0..3
    const int po   = (wv >> 1) * 32;    // pixel quadrant base
    const int oo   = (wv & 1) * 32;     // out-channel quadrant base
    const int g    = lane >> 4;         // k-lanegroup 0..3
    const int ln   = lane & 15;

    float acc[2][2][4];
    {
        float bv0 = bias[oo + ln];
        float bv1 = bias[oo + 16 + ln];
        #pragma unroll
        for (int pf = 0; pf < 2; ++pf)
            #pragma unroll
            for (int r = 0; r < 4; ++r) {
                acc[pf][0][r] = bv0;
                acc[pf][1][r] = bv1;
            }
    }

    // ---- main loop: barrier-free, per-wave independent ----
    for (int t = 0; t < 9; ++t) {
        int kh = t / 3, kw = t - kh * 3;
        f32x4 part[2][2] = {};
        #pragma unroll
        for (int ks = 0; ks < 2; ++ks) {
            bf16x8 af[2], bfr[2];
            #pragma unroll
            for (int pf = 0; pf < 2; ++pf) {
                int col  = po + pf * 16 + ln + kw;      // 0..65
                int rc   = kh * 66 + col;
                int c0   = ks * 32 + g * 8;
                int byte = rc * 128 + ((c0 * 2) ^ ((col & 7) << 4));
                af[pf] = *(const bf16x8*)(arena + byte);
            }
            #pragma unroll
            for (int of = 0; of < 2; ++of) {
                int fi = (wv & 1) * 2 + of;
                bfr[of] = *(const bf16x8*)(wfrag + (((t * 2 + ks) * 4 + fi) * 64 + lane) * 8);
            }
            #pragma unroll
            for (int pf = 0; pf < 2; ++pf)
                #pragma unroll
                for (int of = 0; of < 2; ++of)
                    part[pf][of] = __builtin_amdgcn_mfma_f32_16x16x32_bf16(
                        af[pf], bfr[of], part[pf][of], 0, 0, 0);
        }
        #pragma unroll
        for (int pf = 0; pf < 2; ++pf) {
            f32x4 sv = *(const f32x4*)&siml[t][po + pf * 16 + g * 4];
            #pragma unroll
            for (int of = 0; of < 2; ++of)
                #pragma unroll
                for (int r = 0; r < 4; ++r)
                    acc[pf][of][r] = fmaf(sv[r], part[pf][of][r], acc[pf][of][r]);
        }
    }

    // ---- epilogue: transpose through LDS, coalesced store ----
    __syncthreads();
    #pragma unroll
    for (int pf = 0; pf < 2; ++pf)
        #pragma unroll
        for (int of = 0; of < 2; ++of) {
            int o = oo + of * 16 + ln;
            int p = po + pf * 16 + g * 4;
            f32x4 v = { acc[pf][of][0], acc[pf][of][1],
                        acc[pf][of][2], acc[pf][of][3] };
            *(f32x4*)&ot[o][p] = v;
        }
    __syncthreads();
    {
        int o = tid >> 2, q = tid & 3;
        float* dst = out + (((size_t)(b * O_ + o) * H_ + h) * W_) + w0 + q * 16;
        #pragma unroll
        for (int m = 0; m < 4; ++m) {
            f32x4 v = *(const f32x4*)&ot[o][q * 16 + m * 4];
            *(f32x4*)(dst + m * 4) = v;
        }
    }
}

extern "C" void kernel_launch(void* const* d_in, const int* in_sizes, int n_in,
                              void* d_out, int out_size, void* d_ws, size_t ws_size,
                              hipStream_t stream) {
    const float* x      = (const float*)d_in[0];
    const float* depth  = (const float*)d_in[1];
    const float* weight = (const float*)d_in[2];
    const float* bias   = (const float*)d_in[3];
    float* out          = (float*)d_out;
    unsigned short* wfrag = (unsigned short*)d_ws;   // 73,728 B

    prep_weights<<<dim3(144), dim3(256), 0, stream>>>(weight, wfrag);
    depthconv_mfma<<<dim3(B_ * H_ * 2), dim3(256), 0, stream>>>(
        x, depth, wfrag, bias, out);
}

// Round 3
// 37.067 us; speedup vs baseline: 2.3313x; 2.3313x over previous
//
#include <hip/hip_runtime.h>

#define B_ 8
#define C_ 64
#define O_ 64
#define H_ 128
#define W_ 128

typedef __attribute__((ext_vector_type(8))) short bf16x8;
typedef __attribute__((ext_vector_type(4))) float f32x4;

__device__ __forceinline__ unsigned short f2bf(float v) {
    unsigned u = __float_as_uint(v);
    return (unsigned short)((u + 0x7FFFu + ((u >> 16) & 1u)) >> 16);
}

__device__ __forceinline__ int swz(int col) {   // 16B slot selector, 0..112
    return ((col ^ (col >> 3)) & 7) << 4;
}

// ---- weight prep: wfrag flat = (((t*2+ks)*4+fi)*64 + lane)*8 + j ----
// o = fi*16 + (lane&15), c = ks*32 + ((lane>>4)&3)*8 + j  (MFMA B-frag order)
__global__ void prep_weights(const float* __restrict__ weight,
                             unsigned short* __restrict__ wfrag) {
    int idx = blockIdx.x * 256 + threadIdx.x;
    if (idx >= 9 * 4096) return;
    int j  = idx & 7;
    int l  = (idx >> 3) & 63;
    int fi = (idx >> 9) & 3;
    int ks = (idx >> 11) & 1;
    int t  = idx >> 12;
    int o  = fi * 16 + (l & 15);
    int c  = ks * 32 + ((l >> 4) & 3) * 8 + j;
    wfrag[idx] = f2bf(weight[(o * C_ + c) * 9 + t]);
}

// Block: (b, 4-row group h0, w-half w0) -> 4 output rows x 64 px x 64 o.
// 4 waves, wave wv owns output row h0+wv (all 64 o, 64 px).
// x LDS: bf16, c-innermost: byte(rc = r*66+col, c) = rc*128 + ((2c)^swz(col))
__global__ __launch_bounds__(256, 2)
void depthconv_mfma4(const float* __restrict__ x,
                     const float* __restrict__ depth,
                     const unsigned short* __restrict__ wfrag,
                     const float* __restrict__ bias,
                     float* __restrict__ out) {
    __shared__ __align__(16) unsigned char xs[396 * 128];   // 50688 B
    __shared__ __align__(16) float sim[9][4][64];           // 9216 B
    __shared__ __align__(16) float dt[6][68];               // 1632 B

    const int tid = threadIdx.x;
    const int blk = blockIdx.x;
    const int b   = blk >> 6;            // 64 blocks per batch
    const int rem = blk & 63;
    const int h0  = (rem >> 1) * 4;
    const int w0  = (rem & 1) * 64;

    // ---- stage depth tile (6 x 66) ----
    for (int i = tid; i < 396; i += 256) {
        int r = i / 66, col = i - r * 66;
        int gh = h0 - 1 + r, gw = w0 - 1 + col;
        bool ok = ((unsigned)gh < (unsigned)H_) && ((unsigned)gw < (unsigned)W_);
        int ghc = gh < 0 ? 0 : (gh > H_ - 1 ? H_ - 1 : gh);
        int gwc = gw < 0 ? 0 : (gw > W_ - 1 ? W_ - 1 : gw);
        float v = depth[(b * H_ + ghc) * W_ + gwc];
        dt[r][col] = ok ? v : 0.f;
    }
    __syncthreads();

    // ---- issue x loads (fill the memory queue first) ----
    const int crb = tid >> 4;     // 0..15
    const int q   = tid & 15;     // float4 position along row
    float4 xv[24];
    #pragma unroll
    for (int k = 0; k < 24; ++k) {
        int idx = crb + 16 * k;          // 0..383 = (c,r)
        int c = idx & 63, r = idx >> 6;
        int gh  = h0 - 1 + r;
        int ghc = gh < 0 ? 0 : (gh > H_ - 1 ? H_ - 1 : gh);
        xv[k] = *(const float4*)&x[((b * C_ + c) * H_ + ghc) * W_ + w0 + q * 4];
    }
    float hv[3];
    #pragma unroll
    for (int k = 0; k < 3; ++k) {
        int i = tid + 256 * k;           // 0..767
        int side = i & 1, cr = i >> 1;
        int c = cr & 63, r = cr >> 6;
        int gh = h0 - 1 + r;
        int gw = side ? (w0 + 64) : (w0 - 1);
        bool ok = ((unsigned)gh < (unsigned)H_) && ((unsigned)gw < (unsigned)W_);
        int ghc = gh < 0 ? 0 : (gh > H_ - 1 ? H_ - 1 : gh);
        int gwc = gw < 0 ? 0 : (gw > W_ - 1 ? W_ - 1 : gw);
        float v = x[((b * C_ + c) * H_ + ghc) * W_ + gwc];
        hv[k] = ok ? v : 0.f;
    }

    // ---- sim[t][hr][px] while loads are in flight ----
    {
        int hr = (tid >> 6) & 3, px = tid & 63;
        float dc = dt[hr + 1][px + 1];
        #pragma unroll
        for (int t = 0; t < 9; ++t) {
            const int kh = t / 3, kw = t % 3;   // compile-time
            sim[t][hr][px] = expf(-fabsf(dt[hr + kh][px + kw] - dc));
        }
    }

    // ---- convert + LDS-write x ----
    #pragma unroll
    for (int k = 0; k < 24; ++k) {
        int idx = crb + 16 * k;
        int c = idx & 63, r = idx >> 6;
        int gh = h0 - 1 + r;
        bool okh = (unsigned)gh < (unsigned)H_;
        float vv[4] = {xv[k].x, xv[k].y, xv[k].z, xv[k].w};
        #pragma unroll
        for (int m = 0; m < 4; ++m) {
            int col = 1 + q * 4 + m;
            int rc  = r * 66 + col;
            unsigned short bv = okh ? f2bf(vv[m]) : (unsigned short)0;
            *(unsigned short*)(xs + rc * 128 + ((2 * c) ^ swz(col))) = bv;
        }
    }
    #pragma unroll
    for (int k = 0; k < 3; ++k) {
        int i = tid + 256 * k;
        int side = i & 1, cr = i >> 1;
        int c = cr & 63, r = cr >> 6;
        int col = side ? 65 : 0;
        int rc  = r * 66 + col;
        *(unsigned short*)(xs + rc * 128 + ((2 * c) ^ swz(col))) = f2bf(hv[k]);
    }
    __syncthreads();

    // ---- main loop: barrier-free, wave = output row ----
    const int lane = tid & 63;
    const int hr   = tid >> 6;          // wave = output row
    const int g    = lane >> 4;
    const int ln   = lane & 15;

    float acc[4][4][4];
    #pragma unroll
    for (int of = 0; of < 4; ++of) {
        float bv = bias[of * 16 + ln];
        #pragma unroll
        for (int pf = 0; pf < 4; ++pf)
            #pragma unroll
            for (int r = 0; r < 4; ++r)
                acc[pf][of][r] = bv;
    }

    #pragma unroll 1
    for (int kh = 0; kh < 3; ++kh) {
        #pragma unroll
        for (int kw = 0; kw < 3; ++kw) {
            const int t = kh * 3 + kw;
            bf16x8 bfr[2][4];
            #pragma unroll
            for (int ks = 0; ks < 2; ++ks)
                #pragma unroll
                for (int of = 0; of < 4; ++of)
                    bfr[ks][of] = *(const bf16x8*)(
                        wfrag + (((t * 2 + ks) * 4 + of) * 64 + lane) * 8);

            #pragma unroll
            for (int pf = 0; pf < 4; ++pf) {
                int col = pf * 16 + ln + kw;
                int rcb = (hr + kh) * 66 + col;
                const unsigned char* rowp = xs + rcb * 128;
                bf16x8 af0 = *(const bf16x8*)(rowp + ((2 * (g * 8))      ^ swz(col)));
                bf16x8 af1 = *(const bf16x8*)(rowp + ((2 * (32 + g * 8)) ^ swz(col)));

                f32x4 prt[4] = {};
                #pragma unroll
                for (int of = 0; of < 4; ++of)
                    prt[of] = __builtin_amdgcn_mfma_f32_16x16x32_bf16(
                        af0, bfr[0][of], prt[of], 0, 0, 0);
                #pragma unroll
                for (int of = 0; of < 4; ++of)
                    prt[of] = __builtin_amdgcn_mfma_f32_16x16x32_bf16(
                        af1, bfr[1][of], prt[of], 0, 0, 0);

                f32x4 sv = *(const f32x4*)&sim[t][hr][pf * 16 + g * 4];
                #pragma unroll
                for (int of = 0; of < 4; ++of)
                    #pragma unroll
                    for (int r = 0; r < 4; ++r)
                        acc[pf][of][r] = fmaf(sv[r], prt[of][r], acc[pf][of][r]);
            }
        }
    }

    // ---- direct stores: per (pf,of) one f32x4; 4 g-lanes give 64B chunks ----
    const int h = h0 + hr;
    #pragma unroll
    for (int of = 0; of < 4; ++of) {
        int o = of * 16 + ln;
        float* dst = out + (((size_t)(b * O_ + o) * H_ + h) * W_) + w0;
        #pragma unroll
        for (int pf = 0; pf < 4; ++pf) {
            f32x4 v = { acc[pf][of][0], acc[pf][of][1],
                        acc[pf][of][2], acc[pf][of][3] };
            *(f32x4*)(dst + pf * 16 + g * 4) = v;
        }
    }
}

extern "C" void kernel_launch(void* const* d_in, const int* in_sizes, int n_in,
                              void* d_out, int out_size, void* d_ws, size_t ws_size,
                              hipStream_t stream) {
    const float* x      = (const float*)d_in[0];
    const float* depth  = (const float*)d_in[1];
    const float* weight = (const float*)d_in[2];
    const float* bias   = (const float*)d_in[3];
    float* out          = (float*)d_out;
    unsigned short* wfrag = (unsigned short*)d_ws;   // 73,728 B

    prep_weights<<<dim3(144), dim3(256), 0, stream>>>(weight, wfrag);
    depthconv_mfma4<<<dim3(512), dim3(256), 0, stream>>>(
        x, depth, wfrag, bias, out);
}